// Round 2
// baseline (750.158 us; speedup 1.0000x reference)
//
#include <hip/hip_runtime.h>
#include <hip/hip_fp16.h>

#define TT 512
#define TOTCELL 262144                 // TT*TT packed cells per sample
#define BIGS 1.4426950408889634e10f   // BIG(1e10) * log2(e), scaled domain
#define LOG2E 1.4426950408889634f
#define LN2F 0.69314718055994531f

// packed offset of diagonal kd (cells on diagonals < kd); valid for kd in [0,1024]
__device__ __forceinline__ int diag_off(int kd) {
    return (kd <= 512) ? (kd * (kd + 1)) / 2
                       : TOTCELL - ((1023 - kd) * (1024 - kd)) / 2;
}
__device__ __forceinline__ int diag_start(int kd) {
    return kd > 511 ? kd - 511 : 0;
}

// ---------------------------------------------------------------------------
// Kernel 1: D'[packed anti-diagonal] = |X[n,i]-Z[j]|^2 * log2(e), fp16.
// 64x64 (i,j) tile; compute into LDS; store phase writes diagonal SEGMENTS
// (contiguous runs of halfs) so global stores coalesce.
// ---------------------------------------------------------------------------
__global__ __launch_bounds__(256) void k_dist(const float* __restrict__ X,
                                              const float* __restrict__ Z,
                                              __half* __restrict__ Dd,
                                              float* __restrict__ out) {
    const int n  = blockIdx.x;
    const int i0 = blockIdx.y * 64;
    const int j0 = blockIdx.z * 64;
    __shared__ float  Xt[16][64];   // Xt[c][i_local]
    __shared__ float  Zt[16][64];   // Zt[c][j_local]
    __shared__ __half Dt[64][66];   // stride 66 halfs: 2-way (free) bank pattern
    const int t = threadIdx.x;
    if (n == 0 && i0 == 0 && j0 == 0 && t == 0) out[0] = 0.0f;  // fused zeroing
    {
        const int r  = t >> 2;          // 0..63
        const int cq = (t & 3) * 4;     // 0,4,8,12
        const float4 gx = *(const float4*)&X[((size_t)n * TT + (i0 + r)) * 16 + cq];
        Xt[cq + 0][r] = gx.x; Xt[cq + 1][r] = gx.y;
        Xt[cq + 2][r] = gx.z; Xt[cq + 3][r] = gx.w;
        const float4 gz = *(const float4*)&Z[(size_t)(j0 + r) * 16 + cq];
        Zt[cq + 0][r] = gz.x; Zt[cq + 1][r] = gz.y;
        Zt[cq + 2][r] = gz.z; Zt[cq + 3][r] = gz.w;
    }
    __syncthreads();

    const int iq = (t & 15) * 4;
    const int jq = (t >> 4) * 4;
    float acc[4][4] = {};
#pragma unroll
    for (int c = 0; c < 16; ++c) {
        const float4 xa = *(const float4*)&Xt[c][iq];
        const float4 zb = *(const float4*)&Zt[c][jq];
        const float xs[4] = {xa.x, xa.y, xa.z, xa.w};
        const float zs[4] = {zb.x, zb.y, zb.z, zb.w};
#pragma unroll
        for (int u = 0; u < 4; ++u)
#pragma unroll
            for (int v = 0; v < 4; ++v) {
                const float d = xs[u] - zs[v];
                acc[u][v] = fmaf(d, d, acc[u][v]);
            }
    }
#pragma unroll
    for (int u = 0; u < 4; ++u)
#pragma unroll
        for (int v = 0; v < 4; v += 2) {
            __half2 hv = __floats2half2_rn(acc[u][v] * LOG2E, acc[u][v + 1] * LOG2E);
            *(__half2*)&Dt[iq + u][jq + v] = hv;
        }
    __syncthreads();

    // store phase: wave w handles tile-diagonals dk = w, w+4, ... (<=126)
    const int wv = t >> 6;
    const int ln = t & 63;
    __half* base = Dd + (size_t)n * TOTCELL;
    for (int it = 0; it < 32; ++it) {
        const int dk = wv + it * 4;
        if (dk > 126) break;                       // only wave 3 at it=31
        const int lo  = dk > 63 ? dk - 63 : 0;
        const int hi  = dk < 63 ? dk : 63;
        if (ln <= hi - lo) {
            const int lr = lo + ln;                // local row
            const int ii = i0 + lr;
            const int kd = i0 + j0 + dk;
            base[diag_off(kd) + ii - diag_start(kd)] = Dt[lr][dk - lr];
        }
    }
}

// ---------------------------------------------------------------------------
// Kernel 2: SoftDTW DP. ONE WAVE per sample, 8 rows per lane, no barriers.
// Base-2 scaled domain. No per-cell validity masking: garbage cells never
// feed valid cells; the jj==0 edge is repaired by an exact single-lane fix
// (softmin(u,BIG,BIG) == u exactly in fp32 for u << BIG).
// ---------------------------------------------------------------------------
__global__ __launch_bounds__(64, 1) void k_dp(const __half* __restrict__ Dd,
                                              const float* __restrict__ w,
                                              float* __restrict__ out) {
    const int n = blockIdx.x;
    const int t = threadIdx.x;
    const char* cbase = (const char*)(Dd + (size_t)n * TOTCELL);

    float A[8], B[8];
#pragma unroll
    for (int q = 0; q < 8; ++q) { A[q] = BIGS; B[q] = BIGS; }

    uint4 r0a, r0b; int su0 = 0;    // raw 32B window, even diagonals
    uint4 r1a, r1b; int su1 = 0;    // odd diagonals

    // load the 32B window covering this thread's 8 halfs of diagonal k
    auto LOAD = [&](int k, uint4& qa, uint4& qb, int& su) {
        const int doff  = diag_off(k);
        const int start = diag_start(k);
        const int Ab = 2 * (doff - start) + 16 * t;    // byte offset (>= 0)
        const int B0 = Ab & ~15;
        su = (2 * (doff - start)) & 15;                // wave-uniform shift
        qa = *(const uint4*)(cbase + B0);
        qb = *(const uint4*)(cbase + B0 + (su ? 16 : 0));  // never past sample end
    };
    // funnel-align the window by su bytes and convert 8 halfs -> f32
    auto ALIGN8 = [&](const uint4& qa, const uint4& qb, int su, float dd[8]) {
        uint32_t w0 = qa.x, w1 = qa.y, w2 = qa.z, w3 = qa.w;
        uint32_t w4 = qb.x, w5 = qb.y, w6 = qb.z, w7 = qb.w;
        uint32_t a0, a1, a2, a3, a4;
        switch (su >> 2) {              // wave-uniform scalar branch
            case 0:  a0 = w0; a1 = w1; a2 = w2; a3 = w3; a4 = w4; break;
            case 1:  a0 = w1; a1 = w2; a2 = w3; a3 = w4; a4 = w5; break;
            case 2:  a0 = w2; a1 = w3; a2 = w4; a3 = w5; a4 = w6; break;
            default: a0 = w3; a1 = w4; a2 = w5; a3 = w6; a4 = w7; break;
        }
        if (su & 2) {                   // 16-bit funnel
            a0 = (a0 >> 16) | (a1 << 16); a1 = (a1 >> 16) | (a2 << 16);
            a2 = (a2 >> 16) | (a3 << 16); a3 = (a3 >> 16) | (a4 << 16);
        }
        uint32_t aa[4] = {a0, a1, a2, a3};
#pragma unroll
        for (int j = 0; j < 4; ++j) {
            __half2 hv = *(__half2*)&aa[j];
            float2 fv = __half22float2(hv);
            dd[2 * j] = fv.x; dd[2 * j + 1] = fv.y;
        }
    };

    // One anti-diagonal: P = diag KD-1, Q = diag KD-2 (overwritten with KD).
    auto STEP = [&](int KD, float (&P)[8], float (&Q)[8],
                    uint4& ra, uint4& rb, int& su) {
        float s1 = __shfl_up(P[7], 1);      // R[kd-1] at row 8t-1
        float s2 = __shfl_up(Q[7], 1);      // R[kd-2] at row 8t-1
        if (t == 0) { s1 = BIGS; s2 = BIGS; }
        float dd[8];
        ALIGN8(ra, rb, su, dd);
        int kn = KD + 2; if (kn > 1022) kn = 1022;
        LOAD(kn, ra, rb, su);               // prefetch 2 diagonals ahead
#pragma unroll
        for (int q = 7; q >= 0; --q) {      // descending: Q[q-1] read before write
            const float u1 = q ? P[q - 1] : s1;
            const float u2 = q ? Q[q - 1] : s2;
            const float pl = P[q];
            const float m  = fminf(fminf(u1, pl), u2);
            const float md = __builtin_amdgcn_fmed3f(u1, pl, u2);
            const float mx = fmaxf(fmaxf(u1, pl), u2);
            const float sm = 1.0f + exp2f(m - md) + exp2f(m - mx);  // args <= 0
            Q[q] = dd[q] + m - log2f(sm);
        }
        // jj==0 edge (row == KD): exact value D + up  (D alone at the corner)
        if ((KD >> 3) == t) {               // auto-false for KD >= 512
            switch (KD & 7) {               // uniform scalar switch
                case 0: Q[0] = dd[0] + (KD ? s1 : 0.0f); break;
                case 1: Q[1] = dd[1] + P[0]; break;
                case 2: Q[2] = dd[2] + P[1]; break;
                case 3: Q[3] = dd[3] + P[2]; break;
                case 4: Q[4] = dd[4] + P[3]; break;
                case 5: Q[5] = dd[5] + P[4]; break;
                case 6: Q[6] = dd[6] + P[5]; break;
                case 7: Q[7] = dd[7] + P[6]; break;
            }
        }
    };

    LOAD(0, r0a, r0b, su0);
    LOAD(1, r1a, r1b, su1);
    STEP(0, A, B, r0a, r0b, su0);           // result -> B
    STEP(1, B, A, r1a, r1b, su1);           // result -> A
    for (int kd = 2; kd < 1022; kd += 2) {
        STEP(kd,     A, B, r0a, r0b, su0);
        STEP(kd + 1, B, A, r1a, r1b, su1);
    }
    STEP(1022, A, B, r0a, r0b, su0);        // result -> B

    if (t == 63) atomicAdd(out, w[n] * B[7] * LN2F);
}

extern "C" void kernel_launch(void* const* d_in, const int* in_sizes, int n_in,
                              void* d_out, int out_size, void* d_ws, size_t ws_size,
                              hipStream_t stream) {
    const float* X = (const float*)d_in[0];   // (64, 512, 16) f32
    const float* w = (const float*)d_in[1];   // (64,) f32
    const float* Z = (const float*)d_in[2];   // (512, 16) f32
    float* out = (float*)d_out;               // scalar f32
    __half* Dd = (__half*)d_ws;               // 64 * 262144 * 2 B = 32 MiB exact

    hipLaunchKernelGGL(k_dist, dim3(64, 8, 8), dim3(256), 0, stream, X, Z, Dd, out);
    hipLaunchKernelGGL(k_dp, dim3(64), dim3(64), 0, stream, Dd, w, out);
}

// Round 3
// 741.934 us; speedup vs baseline: 1.0111x; 1.0111x over previous
//
#include <hip/hip_runtime.h>

#define TT 512
#define BIGS 1.4426950408889634e10f   // BIG(1e10) * log2(e), scaled domain
#define LOG2E 1.4426950408889634f
#define M2L  (-2.0f * 1.4426950408889634f)
#define LN2F 0.69314718055994531f

typedef _Float16 h2 __attribute__((ext_vector_type(2)));

__device__ __forceinline__ unsigned pk(float a, float b) {
    h2 v; v.x = (_Float16)a; v.y = (_Float16)b;
    return __builtin_bit_cast(unsigned, v);
}

#if __has_builtin(__builtin_amdgcn_fdot2)
#define FDOT2(a, b, c) __builtin_amdgcn_fdot2(__builtin_bit_cast(h2, (a)), \
                                              __builtin_bit_cast(h2, (b)), (c), false)
#else
__device__ __forceinline__ float fdot2_sw(unsigned a, unsigned b, float c) {
    h2 ha = __builtin_bit_cast(h2, a), hb = __builtin_bit_cast(h2, b);
    return c + (float)ha.x * (float)hb.x + (float)ha.y * (float)hb.y;
}
#define FDOT2(a, b, c) fdot2_sw((a), (b), (c))
#endif

// ---------------------------------------------------------------------------
// Fused SoftDTW: one wave per sample; D recomputed on the fly from registers.
// Lane t owns rows 8t..8t+7 of X (fp16 pairs, 64 VGPRs). Z rows ride a
// register queue shifting across lanes via shfl; lane 0 refills from LDS.
// 8-step unroll makes all queue slot indices compile-time (no shift movs).
// Base-2 scaled domain throughout (values = true * log2(e)).
// ---------------------------------------------------------------------------
__global__ __launch_bounds__(64, 1) void k_fused(const float* __restrict__ X,
                                                 const float* __restrict__ Z,
                                                 const float* __restrict__ w,
                                                 float* __restrict__ out) {
    const int n = blockIdx.x;
    const int t = threadIdx.x;

    __shared__ uint4  ZhU[1024];   // Z rows as 8 x h2 (2 uint4 per row), 16 KiB
    __shared__ float  Zs2f[512];   // LOG2E * |z_row|^2, 2 KiB

    // ---- stage Z into LDS (lane t handles rows 8t..8t+7) ----
#pragma unroll
    for (int k2 = 0; k2 < 8; ++k2) {
        const int r = 8 * t + k2;
        const float4* zp = (const float4*)(Z + (size_t)r * 16);
        const float4 a0 = zp[0], a1 = zp[1], a2 = zp[2], a3 = zp[3];
        float sv = 0.0f;
        sv = fmaf(a0.x, a0.x, sv); sv = fmaf(a0.y, a0.y, sv);
        sv = fmaf(a0.z, a0.z, sv); sv = fmaf(a0.w, a0.w, sv);
        sv = fmaf(a1.x, a1.x, sv); sv = fmaf(a1.y, a1.y, sv);
        sv = fmaf(a1.z, a1.z, sv); sv = fmaf(a1.w, a1.w, sv);
        sv = fmaf(a2.x, a2.x, sv); sv = fmaf(a2.y, a2.y, sv);
        sv = fmaf(a2.z, a2.z, sv); sv = fmaf(a2.w, a2.w, sv);
        sv = fmaf(a3.x, a3.x, sv); sv = fmaf(a3.y, a3.y, sv);
        sv = fmaf(a3.w, a3.w, sv); sv = fmaf(a3.z, a3.z, sv);
        ZhU[2 * r]     = make_uint4(pk(a0.x, a0.y), pk(a0.z, a0.w),
                                    pk(a1.x, a1.y), pk(a1.z, a1.w));
        ZhU[2 * r + 1] = make_uint4(pk(a2.x, a2.y), pk(a2.z, a2.w),
                                    pk(a3.x, a3.y), pk(a3.z, a3.w));
        Zs2f[r] = LOG2E * sv;
    }

    // ---- X rows for this lane -> registers ----
    unsigned Xu[8][8];
    float    xs2[8];
    const float* xp = X + ((size_t)n * TT + 8 * t) * 16;
#pragma unroll
    for (int q = 0; q < 8; ++q) {
        const float4* xr = (const float4*)(xp + q * 16);
        const float4 a0 = xr[0], a1 = xr[1], a2 = xr[2], a3 = xr[3];
        float sv = 0.0f;
        sv = fmaf(a0.x, a0.x, sv); sv = fmaf(a0.y, a0.y, sv);
        sv = fmaf(a0.z, a0.z, sv); sv = fmaf(a0.w, a0.w, sv);
        sv = fmaf(a1.x, a1.x, sv); sv = fmaf(a1.y, a1.y, sv);
        sv = fmaf(a1.z, a1.z, sv); sv = fmaf(a1.w, a1.w, sv);
        sv = fmaf(a2.x, a2.x, sv); sv = fmaf(a2.y, a2.y, sv);
        sv = fmaf(a2.z, a2.z, sv); sv = fmaf(a2.w, a2.w, sv);
        sv = fmaf(a3.x, a3.x, sv); sv = fmaf(a3.y, a3.y, sv);
        sv = fmaf(a3.z, a3.z, sv); sv = fmaf(a3.w, a3.w, sv);
        xs2[q] = LOG2E * sv;
        Xu[q][0] = pk(a0.x, a0.y); Xu[q][1] = pk(a0.z, a0.w);
        Xu[q][2] = pk(a1.x, a1.y); Xu[q][3] = pk(a1.z, a1.w);
        Xu[q][4] = pk(a2.x, a2.y); Xu[q][5] = pk(a2.z, a2.w);
        Xu[q][6] = pk(a3.x, a3.y); Xu[q][7] = pk(a3.z, a3.w);
    }
    __syncthreads();

    // ---- Z register queue init: all slots = row 0 (lane0/slot-q0 must be
    //      exact row 0 for the kd=0 corner; the rest is flushed garbage) ----
    unsigned Zu[8][8];
    float    Zq2[8];
    {
        const uint4 q0 = ZhU[0], q1 = ZhU[1];
        const float qz = Zs2f[0];
        const unsigned fu[8] = {q0.x, q0.y, q0.z, q0.w, q1.x, q1.y, q1.z, q1.w};
#pragma unroll
        for (int s = 0; s < 8; ++s) {
#pragma unroll
            for (int r = 0; r < 8; ++r) Zu[s][r] = fu[r];
            Zq2[s] = qz;
        }
    }

    float A[8], B[8];
#pragma unroll
    for (int q = 0; q < 8; ++q) { A[q] = BIGS; B[q] = BIGS; }

    // One diagonal kd = kd8 + pp. P = diag kd-1, Q = diag kd-2 (becomes kd).
    // Queue mapping: logical cell q (row 8t+q, col kd-8t-q) <-> slot (q-pp)&7.
#define STEP(pp, P, Q)                                                         \
    {                                                                          \
        const int kd = kd8 + (pp);                                             \
        const int fr = (kd + 1 > 511) ? 511 : (kd + 1);                        \
        const uint4 f0 = ZhU[2 * fr], f1 = ZhU[2 * fr + 1];                    \
        const float fz2 = Zs2f[fr];                                            \
        float s1 = __shfl_up(P[7], 1);                                         \
        float s2 = __shfl_up(Q[7], 1);                                         \
        if (t == 0) { s1 = BIGS; s2 = BIGS; }                                  \
        float dd[8];                                                           \
        _Pragma("unroll")                                                      \
        for (int q = 0; q < 8; ++q) {                                          \
            const int s = (q - (pp)) & 7;                                      \
            float acc = 0.0f;                                                  \
            _Pragma("unroll")                                                  \
            for (int r = 0; r < 8; ++r) acc = FDOT2(Zu[s][r], Xu[q][r], acc);  \
            dd[q] = fmaf(M2L, acc, xs2[q] + Zq2[s]);                           \
        }                                                                      \
        _Pragma("unroll")                                                      \
        for (int q = 7; q >= 0; --q) {                                         \
            const float u1 = q ? P[q - 1] : s1;                                \
            const float u2 = q ? Q[q - 1] : s2;                                \
            const float pl = P[q];                                             \
            const float mn = fminf(fminf(u1, pl), u2);                         \
            const float md = __builtin_amdgcn_fmed3f(u1, pl, u2);              \
            const float mx = fmaxf(fmaxf(u1, pl), u2);                         \
            const float sm = 1.0f + exp2f(mn - md) + exp2f(mn - mx);           \
            Q[q] = dd[q] + mn - log2f(sm);                                     \
        }                                                                      \
        if (kd < 512 && t == (kd >> 3)) {                                      \
            Q[(pp)] = dd[(pp)] + ((pp) == 0 ? (kd ? s1 : 0.0f) : P[(pp)-1]);   \
        }                                                                      \
        {                                                                      \
            const int sn = (7 - (pp)) & 7;                                     \
            const unsigned fu[8] = {f0.x, f0.y, f0.z, f0.w,                    \
                                    f1.x, f1.y, f1.z, f1.w};                   \
            _Pragma("unroll")                                                  \
            for (int r = 0; r < 8; ++r) {                                      \
                const unsigned sh = __shfl_up(Zu[sn][r], 1);                   \
                Zu[sn][r] = (t == 0) ? fu[r] : sh;                             \
            }                                                                  \
            const float shz = __shfl_up(Zq2[sn], 1);                           \
            Zq2[sn] = (t == 0) ? fz2 : shz;                                    \
        }                                                                      \
    }

#pragma unroll 1
    for (int kd8 = 0; kd8 < 1024; kd8 += 8) {
        STEP(0, A, B) STEP(1, B, A) STEP(2, A, B) STEP(3, B, A)
        STEP(4, A, B) STEP(5, B, A) STEP(6, A, B) STEP(7, B, A)
    }
#undef STEP

    // diag 1022 result lives in B (pp=6); B[7] at lane 63 = R[T,T] scaled
    if (t == 63) atomicAdd(out, w[n] * B[7] * LN2F);
}

__global__ void k_zero(float* out) {
    if (threadIdx.x == 0) out[0] = 0.0f;
}

extern "C" void kernel_launch(void* const* d_in, const int* in_sizes, int n_in,
                              void* d_out, int out_size, void* d_ws, size_t ws_size,
                              hipStream_t stream) {
    const float* X = (const float*)d_in[0];   // (64, 512, 16) f32
    const float* w = (const float*)d_in[1];   // (64,) f32
    const float* Z = (const float*)d_in[2];   // (512, 16) f32
    float* out = (float*)d_out;               // scalar f32

    hipLaunchKernelGGL(k_zero, dim3(1), dim3(64), 0, stream, out);
    hipLaunchKernelGGL(k_fused, dim3(64), dim3(64), 0, stream, X, Z, w, out);
}